// Round 3
// baseline (33.966 us; speedup 1.0000x reference)
//
#include <hip/hip_runtime.h>

#define SEQ 256
#define NENV 64
#define NGROUPS 12
#define GDIM 128
#define ROWS (SEQ * NENV)          // 16384
#define RPW 4                      // rows per wave (software pipeline depth)
#define WPB 4                      // waves per block
#define NBLOCKS (ROWS / (RPW * WPB))   // 1024 -> 4 blocks/CU, 16 waves/CU

// Kernel 1: v[d] = sum_a Wg[d][a] * Wa[128+a].  512 threads: (d, q) with
// q=quarter; 8 waves issue the 64KB cold read in parallel, LDS-reduce.
__global__ __launch_bounds__(512)
void fold_wg_wa(const float* __restrict__ Wg,
                const float* __restrict__ Wa,
                float* __restrict__ v) {
    __shared__ float part[4][128];
    const int d = threadIdx.x & 127;
    const int q = threadIdx.x >> 7;     // 0..3
    const float4* row = reinterpret_cast<const float4*>(Wg + d * 128 + q * 32);
    const float4* wa4 = reinterpret_cast<const float4*>(Wa + 128 + q * 32);
    float acc = 0.0f;
#pragma unroll
    for (int a = 0; a < 8; ++a) {
        const float4 r = row[a];
        const float4 w = wa4[a];
        acc += r.x * w.x + r.y * w.y + r.z * w.z + r.w * w.w;
    }
    part[q][d] = acc;
    __syncthreads();
    if (threadIdx.x < 128)
        v[d] = part[0][d] + part[1][d] + part[2][d] + part[3][d];
}

// Kernel 2: persistent waves, RPW contiguous rows each, ping-pong prefetch.
// Half-local softmax: each 32-lane half owns the 6 groups {2t+half}.
__global__ __launch_bounds__(WPB * 64)
void group_attn(const float* __restrict__ ge,     // (ROWS, 12, 128)
                const float* __restrict__ v,      // (128)
                float* __restrict__ out_weighted, // (ROWS, 128)
                float* __restrict__ out_weights)  // (ROWS, 12)
{
    const int wave = threadIdx.x >> 6;
    const int lane = threadIdx.x & 63;
    const int wv   = blockIdx.x * WPB + wave;
    const int row0 = wv * RPW;

    const int half = lane >> 5;     // 0: even groups, 1: odd groups
    const int l32  = lane & 31;     // dims [l32*4, l32*4+3]

    const float4 vf = *reinterpret_cast<const float4*>(v + l32 * 4);
    const float* base = ge + (size_t)row0 * (NGROUPS * GDIM) + lane * 4;

    float4 g[2][6];                 // ping-pong row buffers (static idx only)

    // Prologue: load row 0.
#pragma unroll
    for (int t = 0; t < 6; ++t)
        g[0][t] = *reinterpret_cast<const float4*>(base + t * 256);

#pragma unroll
    for (int r = 0; r < RPW; ++r) {
        const int cur = r & 1;
        const int nxt = cur ^ 1;

        // Prefetch next row before computing current (overlap HBM w/ compute).
        if (r + 1 < RPW) {
#pragma unroll
            for (int t = 0; t < 6; ++t)
                g[nxt][t] = *reinterpret_cast<const float4*>(
                    base + (r + 1) * (NGROUPS * GDIM) + t * 256);
        }

        // ---- compute row r from g[cur] ----
        float sc[6];
#pragma unroll
        for (int t = 0; t < 6; ++t) {
            const float4 gt = g[cur][t];
            float p = gt.x * vf.x + gt.y * vf.y + gt.z * vf.z + gt.w * vf.w;
            p += __shfl_xor(p, 1);
            p += __shfl_xor(p, 2);
            p += __shfl_xor(p, 4);
            p += __shfl_xor(p, 8);
            p += __shfl_xor(p, 16);
            sc[t] = p;              // score of group 2t+half
        }

        float mh = fmaxf(fmaxf(fmaxf(sc[0], sc[1]), fmaxf(sc[2], sc[3])),
                         fmaxf(sc[4], sc[5]));
        const float m = fmaxf(mh, __shfl_xor(mh, 32));

        float w[6];
        float sh = 0.0f;
#pragma unroll
        for (int t = 0; t < 6; ++t) {
            w[t] = __expf(sc[t] - m);
            sh += w[t];
        }
        const float s = sh + __shfl_xor(sh, 32);
        const float inv = __builtin_amdgcn_rcpf(s);
#pragma unroll
        for (int t = 0; t < 6; ++t) w[t] *= inv;

        float4 acc;
        acc.x = w[0] * g[cur][0].x; acc.y = w[0] * g[cur][0].y;
        acc.z = w[0] * g[cur][0].z; acc.w = w[0] * g[cur][0].w;
#pragma unroll
        for (int t = 1; t < 6; ++t) {
            acc.x += w[t] * g[cur][t].x;
            acc.y += w[t] * g[cur][t].y;
            acc.z += w[t] * g[cur][t].z;
            acc.w += w[t] * g[cur][t].w;
        }
        acc.x += __shfl_xor(acc.x, 32);
        acc.y += __shfl_xor(acc.y, 32);
        acc.z += __shfl_xor(acc.z, 32);
        acc.w += __shfl_xor(acc.w, 32);

        const int row = row0 + r;
        if (lane < 32) {
            *reinterpret_cast<float4*>(out_weighted + (size_t)row * GDIM + l32 * 4) = acc;
        }

        // Weights: 12 active lanes (l32<6 in each half) cover one contiguous
        // 48B window; static cndmask-chain select (no runtime reg-array idx).
        float wsel = w[0];
        if (l32 == 1) wsel = w[1];
        if (l32 == 2) wsel = w[2];
        if (l32 == 3) wsel = w[3];
        if (l32 == 4) wsel = w[4];
        if (l32 == 5) wsel = w[5];
        if (l32 < NGROUPS / 2) {
            out_weights[(size_t)row * NGROUPS + 2 * l32 + half] = wsel;
        }
    }
}

extern "C" void kernel_launch(void* const* d_in, const int* in_sizes, int n_in,
                              void* d_out, int out_size, void* d_ws, size_t ws_size,
                              hipStream_t stream) {
    // Inputs: 0 robot_states (unused) 1 group_embeddings 2 Wr (unused)
    // 3 br (unused) 4 Wg 5 bg (unused) 6 Wa 7 ba (unused)
    const float* ge = (const float*)d_in[1];
    const float* Wg = (const float*)d_in[4];
    const float* Wa = (const float*)d_in[6];

    float* v = (float*)d_ws;                                   // 128 floats
    float* out_weighted = (float*)d_out;                       // ROWS*128
    float* out_weights  = out_weighted + (size_t)ROWS * GDIM;  // ROWS*12

    fold_wg_wa<<<1, 512, 0, stream>>>(Wg, Wa, v);
    group_attn<<<NBLOCKS, WPB * 64, 0, stream>>>(
        ge, v, out_weighted, out_weights);
}